// Round 13
// baseline (157.021 us; speedup 1.0000x reference)
//
#include <hip/hip_runtime.h>
#include <hip/hip_bf16.h>

typedef unsigned short u16;
typedef unsigned int   u32;
typedef __attribute__((ext_vector_type(8))) short short8;
typedef __attribute__((ext_vector_type(4))) float f32x4;

#define LOG2E 1.4426950408889634f
#define LDK 72  // GEMM LDS row stride (bf16): 144B rows, 16B-aligned, 2-way-max bank aliasing (free)

// RNE f32->bf16 (bit-identical to __float2bfloat16 for finite inputs; validated R2).
static __device__ __forceinline__ u16 f2b(float f) {
    u32 u = __float_as_uint(f);
    u += 0x7fffu + ((u >> 16) & 1u);
    return (u16)(u >> 16);
}
static __device__ __forceinline__ u32 pk2(float a, float b) {
    return (u32)f2b(a) | ((u32)f2b(b) << 16);
}
// Single-instruction pair pack; operand order S0->HIGH half on gfx950 (R1/R4-validated),
// emitted reversed to get a->low, b->high. Used only where pair order is PV-invariant.
static __device__ __forceinline__ u32 cvtpk2(float a, float b) {
    u32 r;
    asm("v_cvt_pk_bf16_f32 %0, %1, %2" : "=v"(r) : "v"(b), "v"(a));
    return r;
}

// ---------------- Kernel 0: prep — X->bf16, Wqkv/Wproj -> bf16 (A rides in qkv launch) -----
// R2 post-mortem: conversion MUST be a full-occupancy streaming pass, never in GEMM staging.
__global__ __launch_bounds__(256) void prep(const float* __restrict__ X,
                                            const float* __restrict__ Wq,
                                            const float* __restrict__ Wp,
                                            u16* __restrict__ xb,
                                            u16* __restrict__ wqb,
                                            u16* __restrict__ wpb) {
    const int bid = blockIdx.x;
    const float* src;
    u16* dst;
    int base;
    if (bid < 2048)      { src = X;  dst = xb;  base = bid * 2048; }
    else if (bid < 2144) { src = Wq; dst = wqb; base = (bid - 2048) * 2048; }
    else                 { src = Wp; dst = wpb; base = (bid - 2144) * 2048; }
    const int i = base + threadIdx.x * 8;
    const float4 a = *(const float4*)(src + i);
    const float4 b = *(const float4*)(src + i + 4);
    uint4 o;
    o.x = pk2(a.x, a.y);
    o.y = pk2(a.z, a.w);
    o.z = pk2(b.x, b.y);
    o.w = pk2(b.z, b.w);
    *(uint4*)(dst + i) = o;
}

// ---------------- Kernel 1: QKV projection + A-conversion plane (R10 champion body) --------
// grid (128, 7): y=0..5 GEMM planes; y=6 = A-conversion (AB = lambda*log2e*A, bf16).
__global__ __launch_bounds__(256) void qkv_gemm(const u16* __restrict__ XB,
                                                const u16* __restrict__ WB,
                                                const float* __restrict__ A,
                                                const float* __restrict__ LAM,
                                                u16* __restrict__ qo,
                                                u16* __restrict__ ko,
                                                u16* __restrict__ vt,
                                                u16* __restrict__ AB) {
    if (blockIdx.y == 6) {
        const float s = LAM[0] * LOG2E;
#pragma unroll
        for (int c = 0; c < 4; ++c) {
            const int i = blockIdx.x * 8192 + c * 2048 + threadIdx.x * 8;
            const float4 a = *(const float4*)(A + i);
            const float4 b = *(const float4*)(A + i + 4);
            uint4 o;
            o.x = pk2(s * a.x, s * a.y);
            o.y = pk2(s * a.z, s * a.w);
            o.z = pk2(s * b.x, s * b.y);
            o.w = pk2(s * b.z, s * b.w);
            *(uint4*)(AB + i) = o;
        }
        return;
    }

    __shared__ u16 SH[2 * 128 * LDK];   // Xs | Ws; reused as transpose buf in v-epilogue
    u16* Xs = SH;
    u16* Ws = SH + 128 * LDK;
    const int t    = threadIdx.x;
    const int m0   = blockIdx.x << 7;
    const int o0   = blockIdx.y << 7;
    const int lane = t & 63;
    const int wid  = t >> 6;
    const int wr   = (wid >> 1) << 6;
    const int wc   = (wid & 1) << 6;
    const int ln   = lane & 15;
    const int quad = lane >> 4;

    const int r  = t >> 1;
    const int hf = (t & 1) << 5;
    const u16* xg = XB + (size_t)(m0 + r) * 256 + hf;
    const u16* wg = WB + (size_t)(o0 + r) * 256 + hf;
    uint4* xls = (uint4*)&Xs[r * LDK + hf];
    uint4* wls = (uint4*)&Ws[r * LDK + hf];

    f32x4 acc[4][4] = {};

    for (int kc = 0; kc < 256; kc += 64) {
        const uint4* xp = (const uint4*)(xg + kc);
        const uint4* wp = (const uint4*)(wg + kc);
        uint4 x0 = xp[0], x1 = xp[1], x2 = xp[2], x3 = xp[3];
        uint4 w0 = wp[0], w1 = wp[1], w2 = wp[2], w3 = wp[3];
        __syncthreads();
        xls[0] = x0; xls[1] = x1; xls[2] = x2; xls[3] = x3;
        wls[0] = w0; wls[1] = w1; wls[2] = w2; wls[3] = w3;
        __syncthreads();
#pragma unroll
        for (int kk = 0; kk < 64; kk += 32) {
            short8 a[4], b[4];
#pragma unroll
            for (int i = 0; i < 4; ++i)
                a[i] = *(const short8*)&Xs[(wr + i * 16 + ln) * LDK + kk + quad * 8];
#pragma unroll
            for (int j = 0; j < 4; ++j)
                b[j] = *(const short8*)&Ws[(wc + j * 16 + ln) * LDK + kk + quad * 8];
#pragma unroll
            for (int i = 0; i < 4; ++i)
#pragma unroll
                for (int j = 0; j < 4; ++j)
                    acc[i][j] = __builtin_amdgcn_mfma_f32_16x16x32_bf16(a[i], b[j], acc[i][j], 0, 0, 0);
        }
    }

    const int which = o0 >> 8;  // 0=q, 1=k, 2=v
    if (which < 2) {
        // q gets 32^-0.5 * log2(e) folded (exp2-based softmax downstream; validated R2)
        const float qscale = (which == 0) ? 0.17677669529663689f * LOG2E : 1.0f;
        u16* dst = (which == 0) ? qo : ko;
#pragma unroll
        for (int i = 0; i < 4; ++i) {
            const int mb = m0 + wr + i * 16 + quad * 4;  // C/D: row = quad*4 + reg
#pragma unroll
            for (int j = 0; j < 4; ++j) {
                const int o   = o0 + wc + j * 16 + ln;   // C/D: col = lane&15
                const int rem = o & 255;
                const int hh  = rem >> 5;
                const int dd  = rem & 31;
#pragma unroll
                for (int rr = 0; rr < 4; ++rr) {
                    const int m  = mb + rr;
                    const int bt = m >> 9;
                    const int n  = m & 511;
                    dst[(((size_t)bt * 8 + hh) * 512 + n) * 32 + dd] = f2b(acc[i][j][rr] * qscale);
                }
            }
        }
    } else {
        // v: transpose 128m x 128o tile via LDS, packed 16B stores to vt[bh][dd][n]
        // cvtpk2 pairs adjacent keys (ml, ml+1) — consistent with attn's Ps pack.
        __syncthreads();
        u16* T = SH;                           // 128 rows (o_local) x stride 136 (m_local)
#pragma unroll
        for (int i = 0; i < 4; ++i) {
            const int ml = wr + i * 16 + quad * 4;
#pragma unroll
            for (int j = 0; j < 4; ++j) {
                const int ol = wc + j * 16 + ln;
                uint2 pv;
                pv.x = cvtpk2(acc[i][j][0], acc[i][j][1]);
                pv.y = cvtpk2(acc[i][j][2], acc[i][j][3]);
                *(uint2*)&T[ol * 136 + ml] = pv;
            }
        }
        __syncthreads();
        const int row = t >> 1;
        const int seg = (t & 1) << 6;
        const int o   = o0 + row;
        const int rem = o & 255;
        const int hh  = rem >> 5;
        const int dd  = rem & 31;
        const int bt  = m0 >> 9;
        u16* dstv = vt + (((size_t)bt * 8 + hh) * 32 + dd) * 512 + (m0 & 511) + seg;
#pragma unroll
        for (int kk2 = 0; kk2 < 8; ++kk2) {
            uint4 val = *(const uint4*)&T[row * 136 + seg + kk2 * 8];
            *(uint4*)(dstv + kk2 * 8) = val;
        }
    }
}

// ---------------- Kernel 2: MFMA flash attention — R13: barrier-free, per-wave direct K/V ----
// R12 post-mortem: intra-wave chain reordering is null — 16 waves/CU already hide it via TLP.
// The unhidden cost is the per-jt __syncthreads() (+vmcnt/lgkmcnt drain) that existed ONLY
// because K/V staging was cooperative across waves. R13: each wave loads K/V fragments
// directly from global (L2-resident by the XCD swizzle: 2MB/XCD). ka load = 64 lanes x 16B =
// one contiguous 1KB region (perfectly coalesced). Ps stays wave-private LDS (within-wave
// ds ordering needs no barrier). ZERO __syncthreads() in the kernel; waves slip freely and
// the compiler can pipeline K loads across jt. Cost: 4x L2 re-read of K/V (~268MB @34.5TB/s,
// overlapped). LDS 10KB/block.
__global__ __launch_bounds__(256, 4) void attn_mfma(const u16* __restrict__ Q,
                                                    const u16* __restrict__ K,
                                                    const u16* __restrict__ VT,
                                                    const u16* __restrict__ AB,
                                                    const int* __restrict__ NF,
                                                    u16* __restrict__ AO) {
    __shared__ u16 Ps[4][32 * 40];    // per-wave P^T chunk [q][32 keys]
    const int t    = threadIdx.x;
    const int w    = t >> 6;
    const int lane = t & 63;
    const int ln   = lane & 15;
    const int quad = lane >> 4;
    const int L    = blockIdx.x;
    const int rr_  = L >> 3;                 // 0..127
    const int qt   = rr_ & 3;
    const int h    = (rr_ >> 2) & 7;
    const int bt   = (L & 7) * 4 + (rr_ >> 5);
    const int bh   = bt * 8 + h;
    const int q0   = qt * 128 + w * 32;
    const size_t base = (size_t)bh * (512 * 32);
    const int b    = bt / NF[0];
    const u16* Ab  = AB + (size_t)b * 512 * 512;
    const u16* Ar0 = Ab + (size_t)(q0 + ln) * 512 + quad * 4;
    const u16* Ar1 = Ab + (size_t)(q0 + 16 + ln) * 512 + quad * 4;

    // per-wave direct-load base pointers
    const u16* Kr  = K  + base + (size_t)ln * 32 + quad * 8;          // + (jt + mt*16)*32
    const u16* Vr0 = VT + base + (size_t)ln * 512 + quad * 8;         // + jt + ks*32
    const u16* Vr1 = VT + base + (size_t)(16 + ln) * 512 + quad * 8;  // + jt + ks*32

    // ---- prologue: preload A regs for jt=0 ----
    uint2 ar[8];
#pragma unroll
    for (int mt = 0; mt < 4; ++mt) {
        ar[2*mt]     = *(const uint2*)(Ar0 + mt * 16);
        ar[2*mt + 1] = *(const uint2*)(Ar1 + mt * 16);
    }

    short8 qf[2];
#pragma unroll
    for (int nt = 0; nt < 2; ++nt)
        qf[nt] = *(const short8*)(Q + base + (size_t)(q0 + nt * 16 + ln) * 32 + quad * 8);

    f32x4 o[2][2] = {};            // O[q-tile][dim-tile], C-layout
    float lsum0 = 0.f, lsum1 = 0.f;   // per-lane partial; reduced once in epilogue

    for (int jt = 0; jt < 512; jt += 64) {
        const int jn = (jt + 64) & 511;   // wrapped: last iter prefetches tile 0 (unused)
        // ---- prefetch NEXT jt's A C-operands ----
        uint2 arn[8];
#pragma unroll
        for (int mt = 0; mt < 4; ++mt) {
            arn[2*mt]     = *(const uint2*)(Ar0 + jn + mt * 16);
            arn[2*mt + 1] = *(const uint2*)(Ar1 + jn + mt * 16);
        }

#pragma unroll
        for (int ks = 0; ks < 2; ++ks) {
            // ---- S chunk: keys ks*32 .. +31 (mt = 2ks, 2ks+1); K direct from global ----
#pragma unroll
            for (int mm = 0; mm < 2; ++mm) {
                const int mt = 2 * ks + mm;
                short8 ka = *(const short8*)(Kr + (size_t)(jt + mt * 16) * 32);
                f32x4 c0, c1;
                c0[0] = __uint_as_float(ar[2*mt].x << 16);   c0[1] = __uint_as_float(ar[2*mt].x & 0xffff0000u);
                c0[2] = __uint_as_float(ar[2*mt].y << 16);   c0[3] = __uint_as_float(ar[2*mt].y & 0xffff0000u);
                c1[0] = __uint_as_float(ar[2*mt+1].x << 16); c1[1] = __uint_as_float(ar[2*mt+1].x & 0xffff0000u);
                c1[2] = __uint_as_float(ar[2*mt+1].y << 16); c1[3] = __uint_as_float(ar[2*mt+1].y & 0xffff0000u);
                __builtin_amdgcn_s_setprio(1);
                const f32x4 s0 = __builtin_amdgcn_mfma_f32_16x16x32_bf16(ka, qf[0], c0, 0, 0, 0);
                const f32x4 s1 = __builtin_amdgcn_mfma_f32_16x16x32_bf16(ka, qf[1], c1, 0, 0, 0);
                __builtin_amdgcn_s_setprio(0);
                const float p00 = __builtin_amdgcn_exp2f(s0[0]), p01 = __builtin_amdgcn_exp2f(s0[1]);
                const float p02 = __builtin_amdgcn_exp2f(s0[2]), p03 = __builtin_amdgcn_exp2f(s0[3]);
                const float p10 = __builtin_amdgcn_exp2f(s1[0]), p11 = __builtin_amdgcn_exp2f(s1[1]);
                const float p12 = __builtin_amdgcn_exp2f(s1[2]), p13 = __builtin_amdgcn_exp2f(s1[3]);
                lsum0 += (p00 + p01) + (p02 + p03);
                lsum1 += (p10 + p11) + (p12 + p13);
                uint2 w0; w0.x = cvtpk2(p00, p01); w0.y = cvtpk2(p02, p03);
                uint2 w1; w1.x = cvtpk2(p10, p11); w1.y = cvtpk2(p12, p13);
                *(uint2*)&Ps[w][ln * 40 + mm * 16 + quad * 4]        = w0;
                *(uint2*)&Ps[w][(16 + ln) * 40 + mm * 16 + quad * 4] = w1;
            }
            // ---- PV chunk: P from wave-private LDS, V direct from global ----
            short8 pa0 = *(const short8*)&Ps[w][ln * 40 + quad * 8];
            short8 pa1 = *(const short8*)&Ps[w][(16 + ln) * 40 + quad * 8];
            short8 vb0 = *(const short8*)(Vr0 + jt + ks * 32);
            short8 vb1 = *(const short8*)(Vr1 + jt + ks * 32);
            __builtin_amdgcn_s_setprio(1);
            o[0][0] = __builtin_amdgcn_mfma_f32_16x16x32_bf16(pa0, vb0, o[0][0], 0, 0, 0);
            o[0][1] = __builtin_amdgcn_mfma_f32_16x16x32_bf16(pa0, vb1, o[0][1], 0, 0, 0);
            o[1][0] = __builtin_amdgcn_mfma_f32_16x16x32_bf16(pa1, vb0, o[1][0], 0, 0, 0);
            o[1][1] = __builtin_amdgcn_mfma_f32_16x16x32_bf16(pa1, vb1, o[1][1], 0, 0, 0);
            __builtin_amdgcn_s_setprio(0);
        }

#pragma unroll
        for (int i = 0; i < 8; ++i) ar[i] = arn[i];
    }

    // ---- epilogue: single cross-quad lsum reduce, O /= l, heads back to [BT,N,D] bf16 ----
    lsum0 += __shfl_xor(lsum0, 16); lsum0 += __shfl_xor(lsum0, 32);
    lsum1 += __shfl_xor(lsum1, 16); lsum1 += __shfl_xor(lsum1, 32);
#pragma unroll
    for (int r = 0; r < 4; ++r) {
        const int src = quad * 4 + r;
        const float i0 = 1.f / __shfl(lsum0, src);
        const float i1 = 1.f / __shfl(lsum1, src);
        const int n0 = qt * 128 + w * 32 + quad * 4 + r;
#pragma unroll
        for (int ntd = 0; ntd < 2; ++ntd) {
            AO[((size_t)bt * 512 + n0) * 256 + h * 32 + ntd * 16 + ln]      = f2b(o[0][ntd][r] * i0);
            AO[((size_t)bt * 512 + n0 + 16) * 256 + h * 32 + ntd * 16 + ln] = f2b(o[1][ntd][r] * i1);
        }
    }
}

// ---------------- Kernel 3: output projection + bias (R6 body: 64-row M-tile, 2 blocks/CU) ----
__global__ __launch_bounds__(256) void proj_gemm(const u16* __restrict__ X,
                                                 const u16* __restrict__ WB,
                                                 const float* __restrict__ BIAS,
                                                 float* __restrict__ OUT) {
    __shared__ u16 Xs[64 * LDK];
    __shared__ u16 Ws[128 * LDK];
    const int t    = threadIdx.x;
    const int m0   = blockIdx.x << 6;
    const int o0   = blockIdx.y << 7;
    const int lane = t & 63;
    const int wid  = t >> 6;
    const int wr   = (wid >> 1) << 5;   // waves cover 2 x 32 rows
    const int wc   = (wid & 1) << 6;
    const int ln   = lane & 15;
    const int quad = lane >> 4;

    // X staging: 64 rows x 64 cols per kc; 4 threads/row, 2x uint4 (32B) each
    const int rx  = t >> 2;
    const int hx  = (t & 3) << 4;
    // W staging: 128 rows x 64 cols per kc; 2 threads/row, 4x uint4 (64B) each
    const int rw  = t >> 1;
    const int hw  = (t & 1) << 5;
    const u16* xg = X  + (size_t)(m0 + rx) * 256 + hx;
    const u16* wg = WB + (size_t)(o0 + rw) * 256 + hw;
    uint4* xls = (uint4*)&Xs[rx * LDK + hx];
    uint4* wls = (uint4*)&Ws[rw * LDK + hw];

    f32x4 acc[2][4] = {};

    for (int kc = 0; kc < 256; kc += 64) {
        const uint4* xp = (const uint4*)(xg + kc);
        const uint4* wp = (const uint4*)(wg + kc);
        uint4 x0 = xp[0], x1 = xp[1];
        uint4 w0 = wp[0], w1 = wp[1], w2 = wp[2], w3 = wp[3];
        __syncthreads();
        xls[0] = x0; xls[1] = x1;
        wls[0] = w0; wls[1] = w1; wls[2] = w2; wls[3] = w3;
        __syncthreads();
#pragma unroll
        for (int kk = 0; kk < 64; kk += 32) {
            short8 a[2], b[4];
#pragma unroll
            for (int i = 0; i < 2; ++i)
                a[i] = *(const short8*)&Xs[(wr + i * 16 + ln) * LDK + kk + quad * 8];
#pragma unroll
            for (int j = 0; j < 4; ++j)
                b[j] = *(const short8*)&Ws[(wc + j * 16 + ln) * LDK + kk + quad * 8];
#pragma unroll
            for (int i = 0; i < 2; ++i)
#pragma unroll
                for (int j = 0; j < 4; ++j)
                    acc[i][j] = __builtin_amdgcn_mfma_f32_16x16x32_bf16(a[i], b[j], acc[i][j], 0, 0, 0);
        }
    }

#pragma unroll
    for (int i = 0; i < 2; ++i) {
        const int mb = m0 + wr + i * 16 + quad * 4;
#pragma unroll
        for (int j = 0; j < 4; ++j) {
            const int o  = o0 + wc + j * 16 + ln;
            const float bo = BIAS[o];
#pragma unroll
            for (int rr = 0; rr < 4; ++rr) {
                const int m = mb + rr;
                OUT[(size_t)m * 256 + o] = acc[i][j][rr] + bo;
            }
        }
    }
}

extern "C" void kernel_launch(void* const* d_in, const int* in_sizes, int n_in,
                              void* d_out, int out_size, void* d_ws, size_t ws_size,
                              hipStream_t stream) {
    (void)in_sizes; (void)n_in; (void)out_size; (void)ws_size;
    const float* x     = (const float*)d_in[0];   // [32,512,256] fp32
    const float* A     = (const float*)d_in[1];   // [4,512,512]  fp32
    const float* Wqkv  = (const float*)d_in[2];   // [768,256]    fp32
    const float* Wproj = (const float*)d_in[3];   // [256,256]    fp32
    const float* bproj = (const float*)d_in[4];   // [256]        fp32
    const float* lam   = (const float*)d_in[5];   // [1]          fp32
    const int*   nf    = (const int*)d_in[6];     // [1]          int32

    float* out = (float*)d_out;                   // [32,512,256] fp32

    // ws (u16 units): q,k,vt,ao (4,194,304 each) + xb (4,194,304) + AB (1,048,576)
    //                + wqb (196,608) + wpb (65,536)  ≈ 44 MB
    u16* q   = (u16*)d_ws;
    u16* k   = q + 4194304;
    u16* vt  = k + 4194304;
    u16* ao  = vt + 4194304;
    u16* xb  = ao + 4194304;
    u16* AB  = xb + 4194304;
    u16* wqb = AB + 1048576;
    u16* wpb = wqb + 196608;

    prep     <<<dim3(2176), 256, 0, stream>>>(x, Wqkv, Wproj, xb, wqb, wpb);
    qkv_gemm <<<dim3(128, 7), 256, 0, stream>>>(xb, wqb, A, lam, q, k, vt, AB);
    attn_mfma<<<dim3(1024), 256, 0, stream>>>(q, k, vt, AB, nf, ao);
    proj_gemm<<<dim3(256, 2), 256, 0, stream>>>(ao, wpb, bproj, out);
}

// Round 14
// 136.295 us; speedup vs baseline: 1.1521x; 1.1521x over previous
//
#include <hip/hip_runtime.h>
#include <hip/hip_bf16.h>

typedef unsigned short u16;
typedef unsigned int   u32;
typedef __attribute__((ext_vector_type(8))) short short8;
typedef __attribute__((ext_vector_type(4))) float f32x4;

#define LOG2E 1.4426950408889634f
#define LDK 72  // GEMM LDS row stride (bf16): 144B rows, 16B-aligned, 2-way-max bank aliasing (free)

// RNE f32->bf16 (bit-identical to __float2bfloat16 for finite inputs; validated R2).
static __device__ __forceinline__ u16 f2b(float f) {
    u32 u = __float_as_uint(f);
    u += 0x7fffu + ((u >> 16) & 1u);
    return (u16)(u >> 16);
}
static __device__ __forceinline__ u32 pk2(float a, float b) {
    return (u32)f2b(a) | ((u32)f2b(b) << 16);
}
// Single-instruction pair pack; operand order S0->HIGH half on gfx950 (R1/R4-validated),
// emitted reversed to get a->low, b->high. Used only where pair order is PV-invariant.
static __device__ __forceinline__ u32 cvtpk2(float a, float b) {
    u32 r;
    asm("v_cvt_pk_bf16_f32 %0, %1, %2" : "=v"(r) : "v"(b), "v"(a));
    return r;
}

// ---------------- Kernel 0: prep — X->bf16, Wqkv/Wproj -> bf16 (A rides in qkv launch) -----
// R2 post-mortem: conversion MUST be a full-occupancy streaming pass, never in GEMM staging.
__global__ __launch_bounds__(256) void prep(const float* __restrict__ X,
                                            const float* __restrict__ Wq,
                                            const float* __restrict__ Wp,
                                            u16* __restrict__ xb,
                                            u16* __restrict__ wqb,
                                            u16* __restrict__ wpb) {
    const int bid = blockIdx.x;
    const float* src;
    u16* dst;
    int base;
    if (bid < 2048)      { src = X;  dst = xb;  base = bid * 2048; }
    else if (bid < 2144) { src = Wq; dst = wqb; base = (bid - 2048) * 2048; }
    else                 { src = Wp; dst = wpb; base = (bid - 2144) * 2048; }
    const int i = base + threadIdx.x * 8;
    const float4 a = *(const float4*)(src + i);
    const float4 b = *(const float4*)(src + i + 4);
    uint4 o;
    o.x = pk2(a.x, a.y);
    o.y = pk2(a.z, a.w);
    o.z = pk2(b.x, b.y);
    o.w = pk2(b.z, b.w);
    *(uint4*)(dst + i) = o;
}

// ---------------- Kernel 1: QKV projection + A-conversion plane (champion body) --------
// grid (128, 7): y=0..5 GEMM planes; y=6 = A-conversion (AB = lambda*log2e*A, bf16) —
// overlaps the GEMM for free (AB is consumed by attn, one launch later). [R10: -2.8us]
// R11's global_load_lds+swizzle staging was NULL here (only 4 kc iters; reg-staged loads
// already issue a full phase pre-barrier; the vmcnt(0) barrier drain is the stall either way).
__global__ __launch_bounds__(256) void qkv_gemm(const u16* __restrict__ XB,
                                                const u16* __restrict__ WB,
                                                const float* __restrict__ A,
                                                const float* __restrict__ LAM,
                                                u16* __restrict__ qo,
                                                u16* __restrict__ ko,
                                                u16* __restrict__ vt,
                                                u16* __restrict__ AB) {
    if (blockIdx.y == 6) {
        const float s = LAM[0] * LOG2E;
#pragma unroll
        for (int c = 0; c < 4; ++c) {
            const int i = blockIdx.x * 8192 + c * 2048 + threadIdx.x * 8;
            const float4 a = *(const float4*)(A + i);
            const float4 b = *(const float4*)(A + i + 4);
            uint4 o;
            o.x = pk2(s * a.x, s * a.y);
            o.y = pk2(s * a.z, s * a.w);
            o.z = pk2(s * b.x, s * b.y);
            o.w = pk2(s * b.z, s * b.w);
            *(uint4*)(AB + i) = o;
        }
        return;
    }

    __shared__ u16 SH[2 * 128 * LDK];   // Xs | Ws; reused as transpose buf in v-epilogue
    u16* Xs = SH;
    u16* Ws = SH + 128 * LDK;
    const int t    = threadIdx.x;
    const int m0   = blockIdx.x << 7;
    const int o0   = blockIdx.y << 7;
    const int lane = t & 63;
    const int wid  = t >> 6;
    const int wr   = (wid >> 1) << 6;
    const int wc   = (wid & 1) << 6;
    const int ln   = lane & 15;
    const int quad = lane >> 4;

    const int r  = t >> 1;
    const int hf = (t & 1) << 5;
    const u16* xg = XB + (size_t)(m0 + r) * 256 + hf;
    const u16* wg = WB + (size_t)(o0 + r) * 256 + hf;
    uint4* xls = (uint4*)&Xs[r * LDK + hf];
    uint4* wls = (uint4*)&Ws[r * LDK + hf];

    f32x4 acc[4][4] = {};

    for (int kc = 0; kc < 256; kc += 64) {
        const uint4* xp = (const uint4*)(xg + kc);
        const uint4* wp = (const uint4*)(wg + kc);
        uint4 x0 = xp[0], x1 = xp[1], x2 = xp[2], x3 = xp[3];
        uint4 w0 = wp[0], w1 = wp[1], w2 = wp[2], w3 = wp[3];
        __syncthreads();
        xls[0] = x0; xls[1] = x1; xls[2] = x2; xls[3] = x3;
        wls[0] = w0; wls[1] = w1; wls[2] = w2; wls[3] = w3;
        __syncthreads();
#pragma unroll
        for (int kk = 0; kk < 64; kk += 32) {
            short8 a[4], b[4];
#pragma unroll
            for (int i = 0; i < 4; ++i)
                a[i] = *(const short8*)&Xs[(wr + i * 16 + ln) * LDK + kk + quad * 8];
#pragma unroll
            for (int j = 0; j < 4; ++j)
                b[j] = *(const short8*)&Ws[(wc + j * 16 + ln) * LDK + kk + quad * 8];
#pragma unroll
            for (int i = 0; i < 4; ++i)
#pragma unroll
                for (int j = 0; j < 4; ++j)
                    acc[i][j] = __builtin_amdgcn_mfma_f32_16x16x32_bf16(a[i], b[j], acc[i][j], 0, 0, 0);
        }
    }

    const int which = o0 >> 8;  // 0=q, 1=k, 2=v
    if (which < 2) {
        // q gets 32^-0.5 * log2(e) folded (exp2-based softmax downstream; validated R2)
        const float qscale = (which == 0) ? 0.17677669529663689f * LOG2E : 1.0f;
        u16* dst = (which == 0) ? qo : ko;
#pragma unroll
        for (int i = 0; i < 4; ++i) {
            const int mb = m0 + wr + i * 16 + quad * 4;  // C/D: row = quad*4 + reg
#pragma unroll
            for (int j = 0; j < 4; ++j) {
                const int o   = o0 + wc + j * 16 + ln;   // C/D: col = lane&15
                const int rem = o & 255;
                const int hh  = rem >> 5;
                const int dd  = rem & 31;
#pragma unroll
                for (int rr = 0; rr < 4; ++rr) {
                    const int m  = mb + rr;
                    const int bt = m >> 9;
                    const int n  = m & 511;
                    dst[(((size_t)bt * 8 + hh) * 512 + n) * 32 + dd] = f2b(acc[i][j][rr] * qscale);
                }
            }
        }
    } else {
        // v: transpose 128m x 128o tile via LDS, packed 16B stores to vt[bh][dd][n]
        // cvtpk2 pairs adjacent keys (ml, ml+1) — consistent with attn's Ps pack.
        __syncthreads();
        u16* T = SH;                           // 128 rows (o_local) x stride 136 (m_local)
#pragma unroll
        for (int i = 0; i < 4; ++i) {
            const int ml = wr + i * 16 + quad * 4;
#pragma unroll
            for (int j = 0; j < 4; ++j) {
                const int ol = wc + j * 16 + ln;
                uint2 pv;
                pv.x = cvtpk2(acc[i][j][0], acc[i][j][1]);
                pv.y = cvtpk2(acc[i][j][2], acc[i][j][3]);
                *(uint2*)&T[ol * 136 + ml] = pv;
            }
        }
        __syncthreads();
        const int row = t >> 1;
        const int seg = (t & 1) << 6;
        const int o   = o0 + row;
        const int rem = o & 255;
        const int hh  = rem >> 5;
        const int dd  = rem & 31;
        const int bt  = m0 >> 9;
        u16* dstv = vt + (((size_t)bt * 8 + hh) * 32 + dd) * 512 + (m0 & 511) + seg;
#pragma unroll
        for (int kk2 = 0; kk2 < 8; ++kk2) {
            uint4 val = *(const uint4*)&T[row * 136 + seg + kk2 * 8];
            *(uint4*)(dstv + kk2 * 8) = val;
        }
    }
}

// ---------------- Kernel 2: MFMA flash attention (champion body, R4) ----------
// L&7 = bt>>2 => each XCD owns 4 bt x all heads x all q-tiles: K+VT = 2MB < 4MB L2.
// Scores carry log2(e) (q-scale and AB), so exp = bare v_exp_f32 (validated R2).
// P-pack via single v_cvt_pk_bf16_f32; per-jt cross-lane lsum reduce deferred to epilogue.
// NEGATIVE results (do not re-add): R5 MFMA-rowsum+unroll2 (+5us); R7-R9 persistent fusion
// (3.4x: allocator pins 64 VGPR); R11 gll+swizzle in qkv (null); R12 Ps dbuf+phase split
// (null: TLP at 16 waves/CU already hides the intra-wave chain); R13 barrier-free direct-
// global K/V (+20us: small LDS -> occupancy-greedy allocator squeezes to 52 VGPR -> spills).
__global__ __launch_bounds__(256, 4) void attn_mfma(const u16* __restrict__ Q,
                                                    const u16* __restrict__ K,
                                                    const u16* __restrict__ VT,
                                                    const u16* __restrict__ AB,
                                                    const int* __restrict__ NF,
                                                    u16* __restrict__ AO) {
    __shared__ u16 Ks[2][64 * 40];    // [buf][key][dim]   80B rows
    __shared__ u16 Vs[2][32 * 72];    // [buf][dim][key]  144B rows (64 keys + 8 pad)
    __shared__ u16 Ps[4][32 * 40];    // per-wave P^T chunk [q][32 keys]
    const int t    = threadIdx.x;
    const int w    = t >> 6;
    const int lane = t & 63;
    const int ln   = lane & 15;
    const int quad = lane >> 4;
    const int L    = blockIdx.x;
    const int rr_  = L >> 3;                 // 0..127
    const int qt   = rr_ & 3;
    const int h    = (rr_ >> 2) & 7;
    const int bt   = (L & 7) * 4 + (rr_ >> 5);
    const int bh   = bt * 8 + h;
    const int q0   = qt * 128 + w * 32;
    const size_t base = (size_t)bh * (512 * 32);
    const int b    = bt / NF[0];
    const u16* Ab  = AB + (size_t)b * 512 * 512;
    const u16* Ar0 = Ab + (size_t)(q0 + ln) * 512 + quad * 4;
    const u16* Ar1 = Ab + (size_t)(q0 + 16 + ln) * 512 + quad * 4;

    // cooperative staging map (2048 bf16 per tile, 256 threads, 1x uint4 each)
    const int krow = t >> 2, kcol = (t & 3) * 8;   // K: 64 rows x 32 dims
    const int vd   = t >> 3, vn   = (t & 7) * 8;   // VT: 32 dims x 64 keys
    const u16* Kg = K + base;
    const u16* Vg = VT + base;

    // ---- prologue: stage jt=0 + preload A regs for jt=0 ----
    {
        uint4 s0 = *(const uint4*)(Kg + (size_t)krow * 32 + kcol);
        uint4 s2 = *(const uint4*)(Vg + (size_t)vd * 512 + vn);
        *(uint4*)&Ks[0][krow * 40 + kcol] = s0;
        *(uint4*)&Vs[0][vd * 72 + vn]     = s2;
    }
    uint2 ar[8];
#pragma unroll
    for (int mt = 0; mt < 4; ++mt) {
        ar[2*mt]     = *(const uint2*)(Ar0 + mt * 16);
        ar[2*mt + 1] = *(const uint2*)(Ar1 + mt * 16);
    }

    short8 qf[2];
#pragma unroll
    for (int nt = 0; nt < 2; ++nt)
        qf[nt] = *(const short8*)(Q + base + (size_t)(q0 + nt * 16 + ln) * 32 + quad * 8);

    f32x4 o[2][2] = {};            // O[q-tile][dim-tile], C-layout
    float lsum0 = 0.f, lsum1 = 0.f;   // per-lane partial; reduced once in epilogue
    __syncthreads();

    int cur = 0;
    for (int jt = 0; jt < 512; jt += 64) {
        const int nxt = cur ^ 1;
        const int jn  = (jt + 64) & 511;   // wrapped: last iter stages tile 0 (unused, harmless)
        // ---- stage next K/V tile into regs (consumed after compute -> full phase of slack) ----
        uint4 t0 = *(const uint4*)(Kg + (size_t)(jn + krow) * 32 + kcol);
        uint4 t2 = *(const uint4*)(Vg + (size_t)vd * 512 + jn + vn);
        // ---- prefetch NEXT jt's A C-operands (used after the barrier -> cannot be sunk) ----
        uint2 arn[8];
#pragma unroll
        for (int mt = 0; mt < 4; ++mt) {
            arn[2*mt]     = *(const uint2*)(Ar0 + jn + mt * 16);
            arn[2*mt + 1] = *(const uint2*)(Ar1 + jn + mt * 16);
        }

#pragma unroll
        for (int ks = 0; ks < 2; ++ks) {
            // ---- S chunk: keys ks*32 .. +31 (mt = 2ks, 2ks+1) ----
#pragma unroll
            for (int mm = 0; mm < 2; ++mm) {
                const int mt = 2 * ks + mm;
                short8 ka = *(const short8*)&Ks[cur][(mt * 16 + ln) * 40 + quad * 8];
                f32x4 c0, c1;
                c0[0] = __uint_as_float(ar[2*mt].x << 16);   c0[1] = __uint_as_float(ar[2*mt].x & 0xffff0000u);
                c0[2] = __uint_as_float(ar[2*mt].y << 16);   c0[3] = __uint_as_float(ar[2*mt].y & 0xffff0000u);
                c1[0] = __uint_as_float(ar[2*mt+1].x << 16); c1[1] = __uint_as_float(ar[2*mt+1].x & 0xffff0000u);
                c1[2] = __uint_as_float(ar[2*mt+1].y << 16); c1[3] = __uint_as_float(ar[2*mt+1].y & 0xffff0000u);
                __builtin_amdgcn_s_setprio(1);
                const f32x4 s0 = __builtin_amdgcn_mfma_f32_16x16x32_bf16(ka, qf[0], c0, 0, 0, 0);
                const f32x4 s1 = __builtin_amdgcn_mfma_f32_16x16x32_bf16(ka, qf[1], c1, 0, 0, 0);
                __builtin_amdgcn_s_setprio(0);
                const float p00 = __builtin_amdgcn_exp2f(s0[0]), p01 = __builtin_amdgcn_exp2f(s0[1]);
                const float p02 = __builtin_amdgcn_exp2f(s0[2]), p03 = __builtin_amdgcn_exp2f(s0[3]);
                const float p10 = __builtin_amdgcn_exp2f(s1[0]), p11 = __builtin_amdgcn_exp2f(s1[1]);
                const float p12 = __builtin_amdgcn_exp2f(s1[2]), p13 = __builtin_amdgcn_exp2f(s1[3]);
                lsum0 += (p00 + p01) + (p02 + p03);
                lsum1 += (p10 + p11) + (p12 + p13);
                uint2 w0; w0.x = cvtpk2(p00, p01); w0.y = cvtpk2(p02, p03);
                uint2 w1; w1.x = cvtpk2(p10, p11); w1.y = cvtpk2(p12, p13);
                *(uint2*)&Ps[w][ln * 40 + mm * 16 + quad * 4]        = w0;
                *(uint2*)&Ps[w][(16 + ln) * 40 + mm * 16 + quad * 4] = w1;
            }
            // ---- PV chunk (within-wave LDS dependency only) ----
            short8 pa0 = *(const short8*)&Ps[w][ln * 40 + quad * 8];
            short8 pa1 = *(const short8*)&Ps[w][(16 + ln) * 40 + quad * 8];
            short8 vb0 = *(const short8*)&Vs[cur][ln * 72 + ks * 32 + quad * 8];
            short8 vb1 = *(const short8*)&Vs[cur][(16 + ln) * 72 + ks * 32 + quad * 8];
            __builtin_amdgcn_s_setprio(1);
            o[0][0] = __builtin_amdgcn_mfma_f32_16x16x32_bf16(pa0, vb0, o[0][0], 0, 0, 0);
            o[0][1] = __builtin_amdgcn_mfma_f32_16x16x32_bf16(pa0, vb1, o[0][1], 0, 0, 0);
            o[1][0] = __builtin_amdgcn_mfma_f32_16x16x32_bf16(pa1, vb0, o[1][0], 0, 0, 0);
            o[1][1] = __builtin_amdgcn_mfma_f32_16x16x32_bf16(pa1, vb1, o[1][1], 0, 0, 0);
            __builtin_amdgcn_s_setprio(0);
        }

        // ---- write staged regs -> next buffer, single barrier per jt ----
        *(uint4*)&Ks[nxt][krow * 40 + kcol] = t0;
        *(uint4*)&Vs[nxt][vd * 72 + vn]     = t2;
        __syncthreads();
#pragma unroll
        for (int i = 0; i < 8; ++i) ar[i] = arn[i];
        cur = nxt;
    }

    // ---- epilogue: single cross-quad lsum reduce, O /= l, heads back to [BT,N,D] bf16 ----
    lsum0 += __shfl_xor(lsum0, 16); lsum0 += __shfl_xor(lsum0, 32);
    lsum1 += __shfl_xor(lsum1, 16); lsum1 += __shfl_xor(lsum1, 32);
#pragma unroll
    for (int r = 0; r < 4; ++r) {
        const int src = quad * 4 + r;
        const float i0 = 1.f / __shfl(lsum0, src);
        const float i1 = 1.f / __shfl(lsum1, src);
        const int n0 = qt * 128 + w * 32 + quad * 4 + r;
#pragma unroll
        for (int ntd = 0; ntd < 2; ++ntd) {
            AO[((size_t)bt * 512 + n0) * 256 + h * 32 + ntd * 16 + ln]      = f2b(o[0][ntd][r] * i0);
            AO[((size_t)bt * 512 + n0 + 16) * 256 + h * 32 + ntd * 16 + ln] = f2b(o[1][ntd][r] * i1);
        }
    }
}

// ---------------- Kernel 3: output projection + bias (R6 body: 64-row M-tile, 2 blocks/CU) ----
__global__ __launch_bounds__(256) void proj_gemm(const u16* __restrict__ X,
                                                 const u16* __restrict__ WB,
                                                 const float* __restrict__ BIAS,
                                                 float* __restrict__ OUT) {
    __shared__ u16 Xs[64 * LDK];
    __shared__ u16 Ws[128 * LDK];
    const int t    = threadIdx.x;
    const int m0   = blockIdx.x << 6;
    const int o0   = blockIdx.y << 7;
    const int lane = t & 63;
    const int wid  = t >> 6;
    const int wr   = (wid >> 1) << 5;   // waves cover 2 x 32 rows
    const int wc   = (wid & 1) << 6;
    const int ln   = lane & 15;
    const int quad = lane >> 4;

    // X staging: 64 rows x 64 cols per kc; 4 threads/row, 2x uint4 (32B) each
    const int rx  = t >> 2;
    const int hx  = (t & 3) << 4;
    // W staging: 128 rows x 64 cols per kc; 2 threads/row, 4x uint4 (64B) each
    const int rw  = t >> 1;
    const int hw  = (t & 1) << 5;
    const u16* xg = X  + (size_t)(m0 + rx) * 256 + hx;
    const u16* wg = WB + (size_t)(o0 + rw) * 256 + hw;
    uint4* xls = (uint4*)&Xs[rx * LDK + hx];
    uint4* wls = (uint4*)&Ws[rw * LDK + hw];

    f32x4 acc[2][4] = {};

    for (int kc = 0; kc < 256; kc += 64) {
        const uint4* xp = (const uint4*)(xg + kc);
        const uint4* wp = (const uint4*)(wg + kc);
        uint4 x0 = xp[0], x1 = xp[1];
        uint4 w0 = wp[0], w1 = wp[1], w2 = wp[2], w3 = wp[3];
        __syncthreads();
        xls[0] = x0; xls[1] = x1;
        wls[0] = w0; wls[1] = w1; wls[2] = w2; wls[3] = w3;
        __syncthreads();
#pragma unroll
        for (int kk = 0; kk < 64; kk += 32) {
            short8 a[2], b[4];
#pragma unroll
            for (int i = 0; i < 2; ++i)
                a[i] = *(const short8*)&Xs[(wr + i * 16 + ln) * LDK + kk + quad * 8];
#pragma unroll
            for (int j = 0; j < 4; ++j)
                b[j] = *(const short8*)&Ws[(wc + j * 16 + ln) * LDK + kk + quad * 8];
#pragma unroll
            for (int i = 0; i < 2; ++i)
#pragma unroll
                for (int j = 0; j < 4; ++j)
                    acc[i][j] = __builtin_amdgcn_mfma_f32_16x16x32_bf16(a[i], b[j], acc[i][j], 0, 0, 0);
        }
    }

#pragma unroll
    for (int i = 0; i < 2; ++i) {
        const int mb = m0 + wr + i * 16 + quad * 4;
#pragma unroll
        for (int j = 0; j < 4; ++j) {
            const int o  = o0 + wc + j * 16 + ln;
            const float bo = BIAS[o];
#pragma unroll
            for (int rr = 0; rr < 4; ++rr) {
                const int m = mb + rr;
                OUT[(size_t)m * 256 + o] = acc[i][j][rr] + bo;
            }
        }
    }
}

extern "C" void kernel_launch(void* const* d_in, const int* in_sizes, int n_in,
                              void* d_out, int out_size, void* d_ws, size_t ws_size,
                              hipStream_t stream) {
    (void)in_sizes; (void)n_in; (void)out_size; (void)ws_size;
    const float* x     = (const float*)d_in[0];   // [32,512,256] fp32
    const float* A     = (const float*)d_in[1];   // [4,512,512]  fp32
    const float* Wqkv  = (const float*)d_in[2];   // [768,256]    fp32
    const float* Wproj = (const float*)d_in[3];   // [256,256]    fp32
    const float* bproj = (const float*)d_in[4];   // [256]        fp32
    const float* lam   = (const float*)d_in[5];   // [1]          fp32
    const int*   nf    = (const int*)d_in[6];     // [1]          int32

    float* out = (float*)d_out;                   // [32,512,256] fp32

    // ws (u16 units): q,k,vt,ao (4,194,304 each) + xb (4,194,304) + AB (1,048,576)
    //                + wqb (196,608) + wpb (65,536)  ≈ 44 MB
    u16* q   = (u16*)d_ws;
    u16* k   = q + 4194304;
    u16* vt  = k + 4194304;
    u16* ao  = vt + 4194304;
    u16* xb  = ao + 4194304;
    u16* AB  = xb + 4194304;
    u16* wqb = AB + 1048576;
    u16* wpb = wqb + 196608;

    prep     <<<dim3(2176), 256, 0, stream>>>(x, Wqkv, Wproj, xb, wqb, wpb);
    qkv_gemm <<<dim3(128, 7), 256, 0, stream>>>(xb, wqb, A, lam, q, k, vt, AB);
    attn_mfma<<<dim3(1024), 256, 0, stream>>>(q, k, vt, AB, nf, ao);
    proj_gemm<<<dim3(256, 2), 256, 0, stream>>>(ao, wpb, bproj, out);
}